// Round 10
// baseline (83.230 us; speedup 1.0000x reference)
//
#include <hip/hip_runtime.h>

#define HORIZON 10
#define NUM_REGIONS 64
#define BB 32
#define TT 12
#define NN 100000

typedef float f32x2 __attribute__((ext_vector_type(2)));
typedef float f32x4 __attribute__((ext_vector_type(4)));
typedef int   i32x2 __attribute__((ext_vector_type(2)));

// Fused kernel, 2 batches per thread (b and b+16) for doubled MLP.
// Plain (cached) x loads, nontemporal out0 stores, LDS->global region sums.
// Blocks with b==0 additionally accumulate region counts.
__global__ __launch_bounds__(256) void mean_kernel(
    const float* __restrict__ x, const int* __restrict__ cid,
    float* __restrict__ out0, float* __restrict__ gsum,
    float* __restrict__ gcount)
{
    __shared__ float lsum[2 * NUM_REGIONS];
    __shared__ float lcnt[NUM_REGIONS];
    const int tid = threadIdx.x;
    const int b  = blockIdx.y;          // 0..15
    const int b2 = b + 16;
    if (tid < NUM_REGIONS) {
        lsum[tid] = 0.0f;
        lsum[NUM_REGIONS + tid] = 0.0f;
        if (b == 0) lcnt[tid] = 0.0f;
    }
    __syncthreads();

    const int i = blockIdx.x * 256 + tid;   // pair index: nodes 2i, 2i+1
    const int n0 = 2 * i;
    if (n0 < NN) {
        float s0 = 0.0f, s1 = 0.0f;         // batch b
        float s2 = 0.0f, s3 = 0.0f;         // batch b2
        #pragma unroll
        for (int t = 0; t < TT; ++t) {
            const f32x4 v = *reinterpret_cast<const f32x4*>(
                x + ((size_t)(b * TT + t) * NN + n0) * 2);
            const f32x4 w = *reinterpret_cast<const f32x4*>(
                x + ((size_t)(b2 * TT + t) * NN + n0) * 2);
            s0 += v.x;  s1 += v.z;
            s2 += w.x;  s3 += w.z;
        }
        const float inv = 1.0f / 12.0f;
        f32x2 mv; mv.x = s0 * inv; mv.y = s1 * inv;
        f32x2 mw; mw.x = s2 * inv; mw.y = s3 * inv;
        const size_t ob1 = (size_t)b  * HORIZON * NN + n0;
        const size_t ob2 = (size_t)b2 * HORIZON * NN + n0;
        #pragma unroll
        for (int h = 0; h < HORIZON; ++h) {
            __builtin_nontemporal_store(
                mv, reinterpret_cast<f32x2*>(out0 + ob1 + (size_t)h * NN));
            __builtin_nontemporal_store(
                mw, reinterpret_cast<f32x2*>(out0 + ob2 + (size_t)h * NN));
        }
        const i32x2 c = *reinterpret_cast<const i32x2*>(cid + n0);
        atomicAdd(&lsum[c.x], mv.x);
        atomicAdd(&lsum[c.y], mv.y);
        atomicAdd(&lsum[NUM_REGIONS + c.x], mw.x);
        atomicAdd(&lsum[NUM_REGIONS + c.y], mw.y);
        if (b == 0) {
            atomicAdd(&lcnt[c.x], 1.0f);
            atomicAdd(&lcnt[c.y], 1.0f);
        }
    }
    __syncthreads();
    if (tid < NUM_REGIONS) {
        atomicAdd(&gsum[b  * NUM_REGIONS + tid], lsum[tid]);
        atomicAdd(&gsum[b2 * NUM_REGIONS + tid], lsum[NUM_REGIONS + tid]);
        if (b == 0) atomicAdd(&gcount[tid], lcnt[tid]);
    }
}

// Regional means broadcast over horizon.
__global__ __launch_bounds__(256) void finalize_kernel(
    const float* __restrict__ gsum, const float* __restrict__ gcount,
    float* __restrict__ out1)
{
    const int idx = blockIdx.x * 256 + threadIdx.x;  // 0 .. B*R-1
    if (idx >= BB * NUM_REGIONS) return;
    const int b = idx >> 6;
    const int r = idx & 63;
    const float v = gsum[idx] / gcount[r];
    const size_t base = (size_t)b * HORIZON * NUM_REGIONS + r;
    #pragma unroll
    for (int h = 0; h < HORIZON; ++h) {
        out1[base + (size_t)h * NUM_REGIONS] = v;
    }
}

extern "C" void kernel_launch(void* const* d_in, const int* in_sizes, int n_in,
                              void* d_out, int out_size, void* d_ws, size_t ws_size,
                              hipStream_t stream) {
    const float* x   = (const float*)d_in[0];
    const int*   cid = (const int*)d_in[1];
    float* out0 = (float*)d_out;
    float* out1 = out0 + (size_t)BB * HORIZON * NN;

    float* gsum   = (float*)d_ws;                 // BB*NUM_REGIONS floats
    float* gcount = gsum + BB * NUM_REGIONS;      // NUM_REGIONS floats

    (void)hipMemsetAsync(d_ws, 0,
                   (BB * NUM_REGIONS + NUM_REGIONS) * sizeof(float), stream);

    dim3 gridA((NN / 2 + 255) / 256, BB / 2);     // (196, 16)
    mean_kernel<<<gridA, 256, 0, stream>>>(x, cid, out0, gsum, gcount);

    finalize_kernel<<<(BB * NUM_REGIONS + 255) / 256, 256, 0, stream>>>(
        gsum, gcount, out1);
}